// Round 13
// baseline (287.244 us; speedup 1.0000x reference)
//
#include <hip/hip_runtime.h>
#include <hip/hip_fp16.h>
#include <stdint.h>

// ---------------------------------------------------------------------------
// GCN 3-layer + edge weights.
// v13: v11 (8-deep gather, best measured) + persistent work-stealing layer
//   blocks: grid=2048 (8/CU resident), tiles pulled via global atomic counter
//   (one per layer) -> no launch quantization, self-balancing tail.
// ---------------------------------------------------------------------------

#define NF 128

typedef unsigned short u16;
typedef unsigned int u32;
typedef __attribute__((ext_vector_type(8))) short short8;   // 8 bf16 = 16 B
typedef __attribute__((ext_vector_type(4))) float f32x4;

__device__ __forceinline__ float bf2f(u16 v) {
    union { unsigned u; float f; } x; x.u = (unsigned)v << 16; return x.f;
}
__device__ __forceinline__ u16 f2bf(float f) {
    union { float f; unsigned u; } x; x.f = f;
    unsigned r = (x.u + 0x7FFFu + ((x.u >> 16) & 1u)) >> 16;
    return (u16)r;
}

// ================= prep_all: hist+rank | cast x | cast/transpose W =========
__global__ __launch_bounds__(256) void prep_all(
    const int* __restrict__ dst, int* __restrict__ counts, int* __restrict__ rank,
    int n_edges,
    const float* __restrict__ x, u16* __restrict__ xb, int n_feat,
    const float* __restrict__ Wr, const float* __restrict__ W1,
    const float* __restrict__ W2, const float* __restrict__ W3,
    const float* __restrict__ Wop, u16* __restrict__ Wt, u16* __restrict__ Wtop,
    int HB, int CB)
{
    int b = blockIdx.x;
    if (b < HB) {
        int e = b * 256 + threadIdx.x;
        if (e < n_edges) rank[e] = atomicAdd(&counts[dst[e]], 1);
    } else if (b < HB + CB) {
        int idx = ((b - HB) * 256 + threadIdx.x) * 4;
        if (idx < n_feat) {
            float4 v = *reinterpret_cast<const float4*>(x + idx);
            ushort4 o;
            o.x = f2bf(v.x); o.y = f2bf(v.y); o.z = f2bf(v.z); o.w = f2bf(v.w);
            *reinterpret_cast<ushort4*>(xb + idx) = o;
        }
    } else {
        int i = (b - HB - CB) * 256 + threadIdx.x;
        if (i < 4 * 16384) {
            int w = i >> 14, r = i & 16383;
            int nn = r >> 7, kk = r & 127;
            const float* W = (w == 0) ? Wr : (w == 1) ? W1 : (w == 2) ? W2 : W3;
            Wt[i] = f2bf(W[kk * NF + nn]);
        } else {
            int r = i - 4 * 16384;
            if (r < 48 * 128) {
                int nn = r >> 7, kk = r & 127;
                Wtop[r] = (nn < 40) ? f2bf(Wop[kk * 40 + nn]) : (u16)0;
            }
        }
    }
}

// ====================== scans (padded-to-4 counts) =========================
// also zeroes the 3 per-layer tile counters (block 0)
__global__ __launch_bounds__(256) void scan_pass1(
    const int* __restrict__ counts, int* __restrict__ bsums,
    int* __restrict__ tilectr, int n)
{
    __shared__ int s[256];
    if (blockIdx.x == 0 && threadIdx.x < 3) tilectr[threadIdx.x] = 0;
    int i = blockIdx.x * 256 + threadIdx.x;
    int c = (i < n) ? counts[i] : 0;
    s[threadIdx.x] = (c + 3) & ~3;
    __syncthreads();
    for (int off = 128; off > 0; off >>= 1) {
        if (threadIdx.x < off) s[threadIdx.x] += s[threadIdx.x + off];
        __syncthreads();
    }
    if (threadIdx.x == 0) bsums[blockIdx.x] = s[0];
}

__global__ __launch_bounds__(256) void scan_pass23(
    int* __restrict__ rowptr, const int* __restrict__ bsums,
    u32* __restrict__ ppairs, int n, int G)
{
    __shared__ int s[256];
    int t = threadIdx.x;
    int bv = (t < G) ? bsums[t] : 0;
    s[t] = bv;
    __syncthreads();
    for (int off = 1; off < 256; off <<= 1) {
        int u = (t >= off) ? s[t - off] : 0;
        __syncthreads();
        s[t] += u;
        __syncthreads();
    }
    int blockoff = (blockIdx.x > 0) ? s[blockIdx.x - 1] : 0;
    int total = s[255];
    __syncthreads();

    int i = blockIdx.x * 256 + t;
    int c = (i < n) ? rowptr[i] : 0;
    int v = (c + 3) & ~3;
    s[t] = v;
    __syncthreads();
    for (int off = 1; off < 256; off <<= 1) {
        int u = (t >= off) ? s[t - off] : 0;
        __syncthreads();
        s[t] += u;
        __syncthreads();
    }
    int excl = s[t] - v + blockoff;
    if (i < n) {
        rowptr[i] = excl;
        for (int k = c; k < v; ++k) ppairs[excl + k] = 0u;  // pad slots
    }
    if (i == 0) rowptr[n] = total;
}

// ============ fill (atomic-free, packed) + res-GEMM, one launch ============
__global__ __launch_bounds__(256) void fill_res(
    const int* __restrict__ src, const int* __restrict__ dst,
    const float* __restrict__ ew, const int* __restrict__ rowptr,
    const int* __restrict__ rank, u32* __restrict__ ppairs, int n_edges,
    const u16* __restrict__ A, const u16* __restrict__ Wt,
    const float* __restrict__ bias, u16* __restrict__ resout, int nrows,
    int HB)
{
    __shared__ u16 Bs[128 * 128];   // used by GEMM branch only
    if (blockIdx.x < (u32)HB) {
        int e = blockIdx.x * 256 + threadIdx.x;
        if (e >= n_edges) return;
        int pos = rowptr[dst[e]] + rank[e];
        ppairs[pos] = ((u32)src[e] << 16) |
                      (u32)__half_as_ushort(__float2half_rn(ew[e]));
        return;
    }
    const int bid = blockIdx.x - HB;
    const int tid = threadIdx.x;
    #pragma unroll
    for (int i = 0; i < 8; i++) {
        int G = tid + i * 256;
        int row = G >> 4, g = G & 15, gs = g ^ (row & 7);
        *reinterpret_cast<short8*>(&Bs[row * NF + gs * 8]) =
            *reinterpret_cast<const short8*>(Wt + (size_t)G * 8);
    }

    const int wave = tid >> 6, lane = tid & 63;
    const int lrow = lane & 15, lk = lane >> 4;
    const int row0 = bid * 64 + wave * 16;
    const int grow = row0 + lrow;

    short8 a[4];
    if (grow < nrows) {
        const u16* Ar = A + (size_t)grow * NF + lk * 8;
        #pragma unroll
        for (int t = 0; t < 4; t++)
            a[t] = *reinterpret_cast<const short8*>(Ar + t * 32);
    } else {
        #pragma unroll
        for (int t = 0; t < 4; t++)
            #pragma unroll
            for (int j = 0; j < 8; j++) a[t][j] = 0;
    }
    __syncthreads();

    f32x4 acc[8];
    #pragma unroll
    for (int c = 0; c < 8; c++) { acc[c][0]=0.f; acc[c][1]=0.f; acc[c][2]=0.f; acc[c][3]=0.f; }

    #pragma unroll
    for (int t = 0; t < 4; t++) {
        #pragma unroll
        for (int c = 0; c < 8; c++) {
            int col = c * 16 + lrow;
            int g = t * 4 + lk, gs = g ^ (col & 7);
            short8 b = *reinterpret_cast<const short8*>(&Bs[col * NF + gs * 8]);
            acc[c] = __builtin_amdgcn_mfma_f32_16x16x32_bf16(a[t], b, acc[c], 0, 0, 0);
        }
    }

    #pragma unroll
    for (int c = 0; c < 8; c++) {
        int col = c * 16 + lrow;
        float bv = bias[col];
        #pragma unroll
        for (int r = 0; r < 4; r++) {
            int orow = row0 + lk * 4 + r;
            if (orow < nrows)
                resout[(size_t)orow * NF + col] = f2bf(acc[c][r] + bv);
        }
    }
}

// ========== fused layer: persistent blocks, gather -> LDS -> MFMA ==========
// Grid = 2048 (8 blocks/CU resident). Tiles of 16 nodes pulled from a global
// atomic counter -> no launch quantization, degree-variance self-balances.
template<int RES, int PROJ>
__global__ __launch_bounds__(256) void layer_gg(
    const u16* __restrict__ X, const int* __restrict__ rowptr,
    const u32* __restrict__ ppairs, const u16* __restrict__ Wt,
    const float* __restrict__ bias, const u16* __restrict__ resid,
    const u16* __restrict__ Wtop, const float* __restrict__ bop,
    u16* __restrict__ hout, float* __restrict__ out, int n_nodes,
    int* __restrict__ ctr, int ntiles)
{
    __shared__ u16 As[16 * 128];                    // 4KB, granule-XOR swizzled
    __shared__ u16 Hs[PROJ ? 16 * 128 : 8];         // 4KB only when PROJ
    __shared__ int s_tile;

    const int tid = threadIdx.x;
    const int wave = tid >> 6, lane = tid & 63;
    const int lrow = lane & 15, lk = lane >> 4;
    const int nl = tid >> 4;          // gather: local node slot 0..15
    const int fl = tid & 15;          // gather: feature granule 0..15

    for (;;) {
        if (tid == 0) s_tile = atomicAdd(ctr, 1);
        __syncthreads();
        const int tile = s_tile;      // barrier below (gather->MFMA) orders
        if (tile >= ntiles) return;   // reads vs next iteration's write
        const int node0 = tile * 16;

        // ---- gather phase: 16 lanes/node, 8 feats (16B)/lane, 8-deep ----
        {
            const int node = node0 + nl;
            float acc[8];
            #pragma unroll
            for (int j = 0; j < 8; j++) acc[j] = 0.f;

            if (node < n_nodes) {
                const u16* xf = X + fl * 8;
                int e0 = rowptr[node];
                int e1 = rowptr[node + 1];
                int e = e0;
                for (; e + 8 <= e1; e += 8) {
                    uint4 pa = *reinterpret_cast<const uint4*>(ppairs + e);
                    uint4 pb = *reinterpret_cast<const uint4*>(ppairs + e + 4);
                    u32 p[8] = {pa.x, pa.y, pa.z, pa.w, pb.x, pb.y, pb.z, pb.w};
                    short8 v[8];
                    #pragma unroll
                    for (int k = 0; k < 8; k++)
                        v[k] = *reinterpret_cast<const short8*>(xf + (size_t)(p[k] >> 16) * NF);
                    #pragma unroll
                    for (int k = 0; k < 8; k++) {
                        float w = __half2float(__ushort_as_half((u16)(p[k] & 0xFFFFu)));
                        #pragma unroll
                        for (int j = 0; j < 8; j++)
                            acc[j] = fmaf(bf2f((u16)v[k][j]), w, acc[j]);
                    }
                }
                if (e < e1) {   // exactly 4 remain (rows padded to %4)
                    uint4 pa = *reinterpret_cast<const uint4*>(ppairs + e);
                    u32 p[4] = {pa.x, pa.y, pa.z, pa.w};
                    short8 v[4];
                    #pragma unroll
                    for (int k = 0; k < 4; k++)
                        v[k] = *reinterpret_cast<const short8*>(xf + (size_t)(p[k] >> 16) * NF);
                    #pragma unroll
                    for (int k = 0; k < 4; k++) {
                        float w = __half2float(__ushort_as_half((u16)(p[k] & 0xFFFFu)));
                        #pragma unroll
                        for (int j = 0; j < 8; j++)
                            acc[j] = fmaf(bf2f((u16)v[k][j]), w, acc[j]);
                    }
                }
            }
            short8 o;
            #pragma unroll
            for (int j = 0; j < 8; j++) o[j] = (short)f2bf(acc[j]);
            int gs = fl ^ (nl & 7);
            *reinterpret_cast<short8*>(&As[nl * NF + gs * 8]) = o;
        }
        __syncthreads();

        // ---- MFMA phase: 16 rows x 128 cols, wave w -> cols [w*32,+32) ----
        short8 a[4];
        #pragma unroll
        for (int t = 0; t < 4; t++) {
            int g = t * 4 + lk, gs = g ^ (lrow & 7);
            a[t] = *reinterpret_cast<const short8*>(&As[lrow * NF + gs * 8]);
        }

        f32x4 acc2[2];
        #pragma unroll
        for (int ct = 0; ct < 2; ct++) { acc2[ct][0]=0.f; acc2[ct][1]=0.f; acc2[ct][2]=0.f; acc2[ct][3]=0.f; }

        #pragma unroll
        for (int t = 0; t < 4; t++) {
            #pragma unroll
            for (int ct = 0; ct < 2; ct++) {
                int col = wave * 32 + ct * 16 + lrow;
                short8 b = *reinterpret_cast<const short8*>(Wt + (size_t)col * NF + (t * 4 + lk) * 8);
                acc2[ct] = __builtin_amdgcn_mfma_f32_16x16x32_bf16(a[t], b, acc2[ct], 0, 0, 0);
            }
        }

        // ---- epilogue: bias (+resid) + relu; write h to global or LDS ----
        #pragma unroll
        for (int ct = 0; ct < 2; ct++) {
            int col = wave * 32 + ct * 16 + lrow;
            float bv = bias[col];
            #pragma unroll
            for (int r = 0; r < 4; r++) {
                int row = lk * 4 + r;
                int node = node0 + row;
                if (node < n_nodes) {
                    float v = acc2[ct][r] + bv;
                    if (RES) v += bf2f(resid[(size_t)node * NF + col]);
                    v = fmaxf(v, 0.f);
                    if (!PROJ) {
                        hout[(size_t)node * NF + col] = f2bf(v);
                    } else {
                        Hs[row * NF + (((col >> 3) ^ (row & 7)) << 3) + (col & 7)] = f2bf(v);
                    }
                }
            }
        }

        if (PROJ) {
            __syncthreads();
            if (wave < 3) {
                short8 pa[4];
                #pragma unroll
                for (int t = 0; t < 4; t++) {
                    int g = t * 4 + lk, gs = g ^ (lrow & 7);
                    pa[t] = *reinterpret_cast<const short8*>(&Hs[lrow * NF + gs * 8]);
                }
                f32x4 pacc;
                pacc[0]=0.f; pacc[1]=0.f; pacc[2]=0.f; pacc[3]=0.f;
                int col = wave * 16 + lrow;
                #pragma unroll
                for (int t = 0; t < 4; t++) {
                    short8 b = *reinterpret_cast<const short8*>(Wtop + (size_t)col * NF + (t * 4 + lk) * 8);
                    pacc = __builtin_amdgcn_mfma_f32_16x16x32_bf16(pa[t], b, pacc, 0, 0, 0);
                }
                if (col < 40) {
                    float bv = bop[col];
                    #pragma unroll
                    for (int r = 0; r < 4; r++) {
                        int node = node0 + lk * 4 + r;
                        if (node < n_nodes)
                            out[(size_t)node * 40 + col] = pacc[r] + bv;
                    }
                }
            }
            __syncthreads();   // Hs reuse across iterations
        }
    }
}

// ============================== launch =====================================

extern "C" void kernel_launch(void* const* d_in, const int* in_sizes, int n_in,
                              void* d_out, int out_size, void* d_ws, size_t ws_size,
                              hipStream_t stream)
{
    const float* x   = (const float*)d_in[0];
    const int*   src = (const int*)d_in[1];
    const int*   dst = (const int*)d_in[2];
    const float* ew  = (const float*)d_in[3];
    const float* Wr  = (const float*)d_in[4];
    const float* br  = (const float*)d_in[5];
    const float* W1  = (const float*)d_in[6];
    const float* b1  = (const float*)d_in[7];
    const float* W2  = (const float*)d_in[8];
    const float* b2  = (const float*)d_in[9];
    const float* W3  = (const float*)d_in[10];
    const float* b3  = (const float*)d_in[11];
    const float* Wop = (const float*)d_in[12];
    const float* bop = (const float*)d_in[13];
    float* out = (float*)d_out;

    const int n_nodes = in_sizes[0] / NF;   // 50000
    const int n_edges = in_sizes[1];        // 640000
    const size_t feat = (size_t)n_nodes * NF;

    // workspace layout
    u16* xb   = (u16*)d_ws;
    u16* h1b  = xb + feat;
    u16* h2b  = h1b + feat;
    u16* resb = h2b + feat;
    u16* Wt   = resb + feat;                 // 4 * 128*128
    u16* Wtop = Wt + 4 * 16384;              // 48*128
    int* rowptr = (int*)(Wtop + 48 * 128);   // n+1 (counts -> padded offsets)
    const int G1 = (n_nodes + 255) / 256;    // 196 (<=256 required)
    int* bsums  = rowptr + (n_nodes + 1);    // G1
    int* tilectr = bsums + (G1 + 1);         // 3 per-layer tile counters
    int* rank   = tilectr + 4;               // n_edges
    u32* ppairs = (u32*)(((uintptr_t)(rank + n_edges) + 15) & ~(uintptr_t)15);

    const int HB = (n_edges + 255) / 256;               // 2500
    const int CB = ((int)feat / 4 + 255) / 256;         // 6250
    const int PB = (4 * 16384 + 48 * 128 + 255) / 256;  // 280
    const int RG = (n_nodes + 63) / 64;                 // 782
    const int ntiles = (n_nodes + 15) / 16;             // 3125
    const int layer_grid = 2048;                        // 8 blocks/CU resident

    // ---- CSR build + casts ----
    hipMemsetAsync(rowptr, 0, (size_t)(n_nodes + 1) * sizeof(int), stream);
    prep_all<<<HB + CB + PB, 256, 0, stream>>>(
        dst, rowptr, rank, n_edges, x, xb, (int)feat,
        Wr, W1, W2, W3, Wop, Wt, Wtop, HB, CB);
    scan_pass1<<<G1, 256, 0, stream>>>(rowptr, bsums, tilectr, n_nodes);
    scan_pass23<<<G1, 256, 0, stream>>>(rowptr, bsums, ppairs, n_nodes, G1);

    // ---- fill ppairs + res = x @ Wr + br (one launch, overlapped) ----
    fill_res<<<HB + RG, 256, 0, stream>>>(
        src, dst, ew, rowptr, rank, ppairs, n_edges,
        xb, Wt, br, resb, n_nodes, HB);

    // ---- 3 fused GCN layers (persistent, work-stealing) ----
    layer_gg<0, 0><<<layer_grid, 256, 0, stream>>>(
        xb, rowptr, ppairs, Wt + 16384, b1, nullptr, nullptr, nullptr,
        h1b, nullptr, n_nodes, tilectr + 0, ntiles);
    layer_gg<0, 0><<<layer_grid, 256, 0, stream>>>(
        h1b, rowptr, ppairs, Wt + 2 * 16384, b2, nullptr, nullptr, nullptr,
        h2b, nullptr, n_nodes, tilectr + 1, ntiles);
    layer_gg<1, 1><<<layer_grid, 256, 0, stream>>>(
        h2b, rowptr, ppairs, Wt + 3 * 16384, b3, resb, Wtop, bop,
        nullptr, out, n_nodes, tilectr + 2, ntiles);
}

// Round 14
// 186.796 us; speedup vs baseline: 1.5377x; 1.5377x over previous
//
#include <hip/hip_runtime.h>
#include <hip/hip_fp16.h>
#include <stdint.h>

// ---------------------------------------------------------------------------
// GCN 3-layer + edge weights.
// v14: revert to v11 (best measured 186.9us). Persistent blocks (v13) and
//   16-deep pipeline (v12) both regressed -> gather is fabric/L3 service-rate
//   bound, insensitive to SW concurrency. Only change vs v11: x-cast at
//   16B/lane (float4 x2 -> short8), halving cast-branch blocks.
// ---------------------------------------------------------------------------

#define NF 128

typedef unsigned short u16;
typedef unsigned int u32;
typedef __attribute__((ext_vector_type(8))) short short8;   // 8 bf16 = 16 B
typedef __attribute__((ext_vector_type(4))) float f32x4;

__device__ __forceinline__ float bf2f(u16 v) {
    union { unsigned u; float f; } x; x.u = (unsigned)v << 16; return x.f;
}
__device__ __forceinline__ u16 f2bf(float f) {
    union { float f; unsigned u; } x; x.f = f;
    unsigned r = (x.u + 0x7FFFu + ((x.u >> 16) & 1u)) >> 16;
    return (u16)r;
}

// ================= prep_all: hist+rank | cast x | cast/transpose W =========
__global__ __launch_bounds__(256) void prep_all(
    const int* __restrict__ dst, int* __restrict__ counts, int* __restrict__ rank,
    int n_edges,
    const float* __restrict__ x, u16* __restrict__ xb, int n_feat,
    const float* __restrict__ Wr, const float* __restrict__ W1,
    const float* __restrict__ W2, const float* __restrict__ W3,
    const float* __restrict__ Wop, u16* __restrict__ Wt, u16* __restrict__ Wtop,
    int HB, int CB)
{
    int b = blockIdx.x;
    if (b < HB) {
        int e = b * 256 + threadIdx.x;
        if (e < n_edges) rank[e] = atomicAdd(&counts[dst[e]], 1);
    } else if (b < HB + CB) {
        int idx = ((b - HB) * 256 + threadIdx.x) * 8;
        if (idx < n_feat) {
            float4 v0 = *reinterpret_cast<const float4*>(x + idx);
            float4 v1 = *reinterpret_cast<const float4*>(x + idx + 4);
            short8 o;
            o[0] = (short)f2bf(v0.x); o[1] = (short)f2bf(v0.y);
            o[2] = (short)f2bf(v0.z); o[3] = (short)f2bf(v0.w);
            o[4] = (short)f2bf(v1.x); o[5] = (short)f2bf(v1.y);
            o[6] = (short)f2bf(v1.z); o[7] = (short)f2bf(v1.w);
            *reinterpret_cast<short8*>(xb + idx) = o;
        }
    } else {
        int i = (b - HB - CB) * 256 + threadIdx.x;
        if (i < 4 * 16384) {
            int w = i >> 14, r = i & 16383;
            int nn = r >> 7, kk = r & 127;
            const float* W = (w == 0) ? Wr : (w == 1) ? W1 : (w == 2) ? W2 : W3;
            Wt[i] = f2bf(W[kk * NF + nn]);
        } else {
            int r = i - 4 * 16384;
            if (r < 48 * 128) {
                int nn = r >> 7, kk = r & 127;
                Wtop[r] = (nn < 40) ? f2bf(Wop[kk * 40 + nn]) : (u16)0;
            }
        }
    }
}

// ====================== scans (padded-to-4 counts) =========================
__global__ __launch_bounds__(256) void scan_pass1(
    const int* __restrict__ counts, int* __restrict__ bsums, int n)
{
    __shared__ int s[256];
    int i = blockIdx.x * 256 + threadIdx.x;
    int c = (i < n) ? counts[i] : 0;
    s[threadIdx.x] = (c + 3) & ~3;
    __syncthreads();
    for (int off = 128; off > 0; off >>= 1) {
        if (threadIdx.x < off) s[threadIdx.x] += s[threadIdx.x + off];
        __syncthreads();
    }
    if (threadIdx.x == 0) bsums[blockIdx.x] = s[0];
}

__global__ __launch_bounds__(256) void scan_pass23(
    int* __restrict__ rowptr, const int* __restrict__ bsums,
    u32* __restrict__ ppairs, int n, int G)
{
    __shared__ int s[256];
    int t = threadIdx.x;
    int bv = (t < G) ? bsums[t] : 0;
    s[t] = bv;
    __syncthreads();
    for (int off = 1; off < 256; off <<= 1) {
        int u = (t >= off) ? s[t - off] : 0;
        __syncthreads();
        s[t] += u;
        __syncthreads();
    }
    int blockoff = (blockIdx.x > 0) ? s[blockIdx.x - 1] : 0;
    int total = s[255];
    __syncthreads();

    int i = blockIdx.x * 256 + t;
    int c = (i < n) ? rowptr[i] : 0;
    int v = (c + 3) & ~3;
    s[t] = v;
    __syncthreads();
    for (int off = 1; off < 256; off <<= 1) {
        int u = (t >= off) ? s[t - off] : 0;
        __syncthreads();
        s[t] += u;
        __syncthreads();
    }
    int excl = s[t] - v + blockoff;
    if (i < n) {
        rowptr[i] = excl;
        for (int k = c; k < v; ++k) ppairs[excl + k] = 0u;  // pad slots
    }
    if (i == 0) rowptr[n] = total;
}

// ============ fill (atomic-free, packed) + res-GEMM, one launch ============
__global__ __launch_bounds__(256) void fill_res(
    const int* __restrict__ src, const int* __restrict__ dst,
    const float* __restrict__ ew, const int* __restrict__ rowptr,
    const int* __restrict__ rank, u32* __restrict__ ppairs, int n_edges,
    const u16* __restrict__ A, const u16* __restrict__ Wt,
    const float* __restrict__ bias, u16* __restrict__ resout, int nrows,
    int HB)
{
    __shared__ u16 Bs[128 * 128];   // used by GEMM branch only
    if (blockIdx.x < (u32)HB) {
        int e = blockIdx.x * 256 + threadIdx.x;
        if (e >= n_edges) return;
        int pos = rowptr[dst[e]] + rank[e];
        ppairs[pos] = ((u32)src[e] << 16) |
                      (u32)__half_as_ushort(__float2half_rn(ew[e]));
        return;
    }
    const int bid = blockIdx.x - HB;
    const int tid = threadIdx.x;
    #pragma unroll
    for (int i = 0; i < 8; i++) {
        int G = tid + i * 256;
        int row = G >> 4, g = G & 15, gs = g ^ (row & 7);
        *reinterpret_cast<short8*>(&Bs[row * NF + gs * 8]) =
            *reinterpret_cast<const short8*>(Wt + (size_t)G * 8);
    }

    const int wave = tid >> 6, lane = tid & 63;
    const int lrow = lane & 15, lk = lane >> 4;
    const int row0 = bid * 64 + wave * 16;
    const int grow = row0 + lrow;

    short8 a[4];
    if (grow < nrows) {
        const u16* Ar = A + (size_t)grow * NF + lk * 8;
        #pragma unroll
        for (int t = 0; t < 4; t++)
            a[t] = *reinterpret_cast<const short8*>(Ar + t * 32);
    } else {
        #pragma unroll
        for (int t = 0; t < 4; t++)
            #pragma unroll
            for (int j = 0; j < 8; j++) a[t][j] = 0;
    }
    __syncthreads();

    f32x4 acc[8];
    #pragma unroll
    for (int c = 0; c < 8; c++) { acc[c][0]=0.f; acc[c][1]=0.f; acc[c][2]=0.f; acc[c][3]=0.f; }

    #pragma unroll
    for (int t = 0; t < 4; t++) {
        #pragma unroll
        for (int c = 0; c < 8; c++) {
            int col = c * 16 + lrow;
            int g = t * 4 + lk, gs = g ^ (col & 7);
            short8 b = *reinterpret_cast<const short8*>(&Bs[col * NF + gs * 8]);
            acc[c] = __builtin_amdgcn_mfma_f32_16x16x32_bf16(a[t], b, acc[c], 0, 0, 0);
        }
    }

    #pragma unroll
    for (int c = 0; c < 8; c++) {
        int col = c * 16 + lrow;
        float bv = bias[col];
        #pragma unroll
        for (int r = 0; r < 4; r++) {
            int orow = row0 + lk * 4 + r;
            if (orow < nrows)
                resout[(size_t)orow * NF + col] = f2bf(acc[c][r] + bv);
        }
    }
}

// ================= fused layer: gather -> LDS -> MFMA ======================
// Block = 256 thr = 16 nodes. Gather: 16 lanes/node, 8-deep edge pipeline.
template<int RES, int PROJ>
__global__ __launch_bounds__(256) void layer_gg(
    const u16* __restrict__ X, const int* __restrict__ rowptr,
    const u32* __restrict__ ppairs, const u16* __restrict__ Wt,
    const float* __restrict__ bias, const u16* __restrict__ resid,
    const u16* __restrict__ Wtop, const float* __restrict__ bop,
    u16* __restrict__ hout, float* __restrict__ out, int n_nodes)
{
    __shared__ u16 As[16 * 128];                    // 4KB, granule-XOR swizzled
    __shared__ u16 Hs[PROJ ? 16 * 128 : 8];         // 4KB only when PROJ

    const int tid = threadIdx.x;
    const int node0 = blockIdx.x * 16;

    // ---- gather phase: 16 lanes/node, 8 feats (16B) per lane ----
    {
        const int nl = tid >> 4;          // local node slot 0..15
        const int fl = tid & 15;          // feature granule 0..15
        const int node = node0 + nl;
        float acc[8];
        #pragma unroll
        for (int j = 0; j < 8; j++) acc[j] = 0.f;

        if (node < n_nodes) {
            const u16* xf = X + fl * 8;
            int e0 = rowptr[node];
            int e1 = rowptr[node + 1];
            int e = e0;
            for (; e + 8 <= e1; e += 8) {
                uint4 pa = *reinterpret_cast<const uint4*>(ppairs + e);
                uint4 pb = *reinterpret_cast<const uint4*>(ppairs + e + 4);
                u32 p[8] = {pa.x, pa.y, pa.z, pa.w, pb.x, pb.y, pb.z, pb.w};
                short8 v[8];
                #pragma unroll
                for (int k = 0; k < 8; k++)
                    v[k] = *reinterpret_cast<const short8*>(xf + (size_t)(p[k] >> 16) * NF);
                #pragma unroll
                for (int k = 0; k < 8; k++) {
                    float w = __half2float(__ushort_as_half((u16)(p[k] & 0xFFFFu)));
                    #pragma unroll
                    for (int j = 0; j < 8; j++)
                        acc[j] = fmaf(bf2f((u16)v[k][j]), w, acc[j]);
                }
            }
            if (e < e1) {   // exactly 4 remain (rows padded to %4)
                uint4 pa = *reinterpret_cast<const uint4*>(ppairs + e);
                u32 p[4] = {pa.x, pa.y, pa.z, pa.w};
                short8 v[4];
                #pragma unroll
                for (int k = 0; k < 4; k++)
                    v[k] = *reinterpret_cast<const short8*>(xf + (size_t)(p[k] >> 16) * NF);
                #pragma unroll
                for (int k = 0; k < 4; k++) {
                    float w = __half2float(__ushort_as_half((u16)(p[k] & 0xFFFFu)));
                    #pragma unroll
                    for (int j = 0; j < 8; j++)
                        acc[j] = fmaf(bf2f((u16)v[k][j]), w, acc[j]);
                }
            }
        }
        short8 o;
        #pragma unroll
        for (int j = 0; j < 8; j++) o[j] = (short)f2bf(acc[j]);
        int gs = fl ^ (nl & 7);
        *reinterpret_cast<short8*>(&As[nl * NF + gs * 8]) = o;
    }
    __syncthreads();

    // ---- MFMA phase: 16 rows x 128 cols, wave w -> cols [w*32, w*32+32) ----
    const int wave = tid >> 6, lane = tid & 63;
    const int lrow = lane & 15, lk = lane >> 4;

    short8 a[4];
    #pragma unroll
    for (int t = 0; t < 4; t++) {
        int g = t * 4 + lk, gs = g ^ (lrow & 7);
        a[t] = *reinterpret_cast<const short8*>(&As[lrow * NF + gs * 8]);
    }

    f32x4 acc2[2];
    #pragma unroll
    for (int ct = 0; ct < 2; ct++) { acc2[ct][0]=0.f; acc2[ct][1]=0.f; acc2[ct][2]=0.f; acc2[ct][3]=0.f; }

    #pragma unroll
    for (int t = 0; t < 4; t++) {
        #pragma unroll
        for (int ct = 0; ct < 2; ct++) {
            int col = wave * 32 + ct * 16 + lrow;
            short8 b = *reinterpret_cast<const short8*>(Wt + (size_t)col * NF + (t * 4 + lk) * 8);
            acc2[ct] = __builtin_amdgcn_mfma_f32_16x16x32_bf16(a[t], b, acc2[ct], 0, 0, 0);
        }
    }

    // ---- epilogue: bias (+resid) + relu; write h to global or LDS ----
    #pragma unroll
    for (int ct = 0; ct < 2; ct++) {
        int col = wave * 32 + ct * 16 + lrow;
        float bv = bias[col];
        #pragma unroll
        for (int r = 0; r < 4; r++) {
            int row = lk * 4 + r;
            int node = node0 + row;
            if (node < n_nodes) {
                float v = acc2[ct][r] + bv;
                if (RES) v += bf2f(resid[(size_t)node * NF + col]);
                v = fmaxf(v, 0.f);
                if (!PROJ) {
                    hout[(size_t)node * NF + col] = f2bf(v);
                } else {
                    Hs[row * NF + (((col >> 3) ^ (row & 7)) << 3) + (col & 7)] = f2bf(v);
                }
            }
        }
    }

    if (PROJ) {
        __syncthreads();
        if (wave < 3) {
            short8 pa[4];
            #pragma unroll
            for (int t = 0; t < 4; t++) {
                int g = t * 4 + lk, gs = g ^ (lrow & 7);
                pa[t] = *reinterpret_cast<const short8*>(&Hs[lrow * NF + gs * 8]);
            }
            f32x4 pacc;
            pacc[0]=0.f; pacc[1]=0.f; pacc[2]=0.f; pacc[3]=0.f;
            int col = wave * 16 + lrow;
            #pragma unroll
            for (int t = 0; t < 4; t++) {
                short8 b = *reinterpret_cast<const short8*>(Wtop + (size_t)col * NF + (t * 4 + lk) * 8);
                pacc = __builtin_amdgcn_mfma_f32_16x16x32_bf16(pa[t], b, pacc, 0, 0, 0);
            }
            if (col < 40) {
                float bv = bop[col];
                #pragma unroll
                for (int r = 0; r < 4; r++) {
                    int node = node0 + lk * 4 + r;
                    if (node < n_nodes)
                        out[(size_t)node * 40 + col] = pacc[r] + bv;
                }
            }
        }
    }
}

// ============================== launch =====================================

extern "C" void kernel_launch(void* const* d_in, const int* in_sizes, int n_in,
                              void* d_out, int out_size, void* d_ws, size_t ws_size,
                              hipStream_t stream)
{
    const float* x   = (const float*)d_in[0];
    const int*   src = (const int*)d_in[1];
    const int*   dst = (const int*)d_in[2];
    const float* ew  = (const float*)d_in[3];
    const float* Wr  = (const float*)d_in[4];
    const float* br  = (const float*)d_in[5];
    const float* W1  = (const float*)d_in[6];
    const float* b1  = (const float*)d_in[7];
    const float* W2  = (const float*)d_in[8];
    const float* b2  = (const float*)d_in[9];
    const float* W3  = (const float*)d_in[10];
    const float* b3  = (const float*)d_in[11];
    const float* Wop = (const float*)d_in[12];
    const float* bop = (const float*)d_in[13];
    float* out = (float*)d_out;

    const int n_nodes = in_sizes[0] / NF;   // 50000
    const int n_edges = in_sizes[1];        // 640000
    const size_t feat = (size_t)n_nodes * NF;

    // workspace layout
    u16* xb   = (u16*)d_ws;
    u16* h1b  = xb + feat;
    u16* h2b  = h1b + feat;
    u16* resb = h2b + feat;
    u16* Wt   = resb + feat;                 // 4 * 128*128
    u16* Wtop = Wt + 4 * 16384;              // 48*128
    int* rowptr = (int*)(Wtop + 48 * 128);   // n+1 (counts -> padded offsets)
    const int G1 = (n_nodes + 255) / 256;    // 196 (<=256 required)
    int* bsums  = rowptr + (n_nodes + 1);    // G1
    int* rank   = bsums + (G1 + 1);          // n_edges
    u32* ppairs = (u32*)(((uintptr_t)(rank + n_edges) + 15) & ~(uintptr_t)15);

    const int HB = (n_edges + 255) / 256;               // 2500
    const int CB = ((int)feat / 8 + 255) / 256;         // 3125
    const int PB = (4 * 16384 + 48 * 128 + 255) / 256;  // 280
    const int RG = (n_nodes + 63) / 64;                 // 782
    const int layer_grid = (n_nodes + 15) / 16;         // 3125

    // ---- CSR build + casts ----
    hipMemsetAsync(rowptr, 0, (size_t)(n_nodes + 1) * sizeof(int), stream);
    prep_all<<<HB + CB + PB, 256, 0, stream>>>(
        dst, rowptr, rank, n_edges, x, xb, (int)feat,
        Wr, W1, W2, W3, Wop, Wt, Wtop, HB, CB);
    scan_pass1<<<G1, 256, 0, stream>>>(rowptr, bsums, n_nodes);
    scan_pass23<<<G1, 256, 0, stream>>>(rowptr, bsums, ppairs, n_nodes, G1);

    // ---- fill ppairs + res = x @ Wr + br (one launch, overlapped) ----
    fill_res<<<HB + RG, 256, 0, stream>>>(
        src, dst, ew, rowptr, rank, ppairs, n_edges,
        xb, Wt, br, resb, n_nodes, HB);

    // ---- 3 fused GCN layers ----
    layer_gg<0, 0><<<layer_grid, 256, 0, stream>>>(
        xb, rowptr, ppairs, Wt + 16384, b1, nullptr, nullptr, nullptr,
        h1b, nullptr, n_nodes);
    layer_gg<0, 0><<<layer_grid, 256, 0, stream>>>(
        h1b, rowptr, ppairs, Wt + 2 * 16384, b2, nullptr, nullptr, nullptr,
        h2b, nullptr, n_nodes);
    layer_gg<1, 1><<<layer_grid, 256, 0, stream>>>(
        h2b, rowptr, ppairs, Wt + 3 * 16384, b3, resb, Wtop, bop,
        nullptr, out, n_nodes);
}